// Round 1
// baseline (44.554 us; speedup 1.0000x reference)
//
#include <hip/hip_runtime.h>

#define IMG_H 1024
#define IMG_W 1024

// Each thread computes the Sobel-X / Sobel-Y block variance (4x4 non-overlapping
// block) for one block of one image, using separable Sobel:
//   SOBEL_X = [1,2,1]^T (vert) x [-1,0,1] (horiz)
//   SOBEL_Y = [-1,0,1]^T (vert) x [ 1,2,1] (horiz)
// Zero padding = 1 (matches nn.Conv2d / lax.conv with padding ((1,1),(1,1))).
__device__ __forceinline__ void block_grad_var(const float* __restrict__ img,
                                               int px, int py,
                                               float& varX, float& varY) {
    float hA[6][4];  // horizontal [-1,0,1] filtered, rows py-1..py+4, cols px..px+3
    float hB[6][4];  // horizontal [ 1,2,1] filtered
#pragma unroll
    for (int ry = 0; ry < 6; ++ry) {
        int y = py - 1 + ry;
        float v0, v1, v2, v3, v4, v5;  // cols px-1 .. px+4
        if (y >= 0 && y < IMG_H) {
            const float* row = img + (size_t)y * IMG_W;
            float4 m = *reinterpret_cast<const float4*>(row + px);  // px % 4 == 0
            v1 = m.x; v2 = m.y; v3 = m.z; v4 = m.w;
            v0 = (px > 0)           ? row[px - 1] : 0.f;
            v5 = (px + 4 < IMG_W)   ? row[px + 4] : 0.f;
        } else {
            v0 = v1 = v2 = v3 = v4 = v5 = 0.f;
        }
        float v[6] = {v0, v1, v2, v3, v4, v5};
#pragma unroll
        for (int c = 0; c < 4; ++c) {
            hA[ry][c] = v[c + 2] - v[c];
            hB[ry][c] = v[c] + 2.f * v[c + 1] + v[c + 2];
        }
    }
    float sX = 0.f, sX2 = 0.f, sY = 0.f, sY2 = 0.f;
#pragma unroll
    for (int yy = 0; yy < 4; ++yy) {
#pragma unroll
        for (int c = 0; c < 4; ++c) {
            float gx = hA[yy][c] + 2.f * hA[yy + 1][c] + hA[yy + 2][c];
            float gy = hB[yy + 2][c] - hB[yy][c];
            sX += gx; sX2 += gx * gx;
            sY += gy; sY2 += gy * gy;
        }
    }
    float mX = sX * 0.0625f, mY = sY * 0.0625f;
    varX = sX2 * 0.0625f - mX * mX;
    varY = sY2 * 0.0625f - mY * mY;
}

// Grid: 16 images * 16*16 tiles = 4096 workgroups of 256 threads.
// Each workgroup covers a 64x64 pixel tile (16x16 blocks of 4x4).
__global__ __launch_bounds__(256) void gvl_main(const float* __restrict__ out_img,
                                                const float* __restrict__ tgt_img,
                                                float* __restrict__ partial) {
    int wg   = blockIdx.x;
    int img  = wg >> 8;
    int tile = wg & 255;
    int ty = tile >> 4, tx = tile & 15;
    int t  = threadIdx.x;
    int by = t >> 4, bx = t & 15;
    int py = ty * 64 + by * 4;
    int px = tx * 64 + bx * 4;
    size_t base = (size_t)img * (IMG_H * IMG_W);

    float vXo, vYo, vXt, vYt;
    block_grad_var(out_img + base, px, py, vXo, vYo);
    block_grad_var(tgt_img + base, px, py, vXt, vYt);

    float dX = vXo - vXt, dY = vYo - vYt;
    float val = dX * dX + dY * dY;

    // wave (64-lane) tree reduction
#pragma unroll
    for (int off = 32; off > 0; off >>= 1) val += __shfl_down(val, off);
    __shared__ float ws[4];
    if ((t & 63) == 0) ws[t >> 6] = val;
    __syncthreads();
    if (t == 0) partial[wg] = ws[0] + ws[1] + ws[2] + ws[3];
}

__global__ __launch_bounds__(256) void gvl_final(const float* __restrict__ partial,
                                                 float* __restrict__ out) {
    int t = threadIdx.x;
    float s = 0.f;
#pragma unroll
    for (int i = 0; i < 16; ++i) s += partial[t + i * 256];
#pragma unroll
    for (int off = 32; off > 0; off >>= 1) s += __shfl_down(s, off);
    __shared__ float ws[4];
    if ((t & 63) == 0) ws[t >> 6] = s;
    __syncthreads();
    if (t == 0) out[0] = ws[0] + ws[1] + ws[2] + ws[3];
}

extern "C" void kernel_launch(void* const* d_in, const int* in_sizes, int n_in,
                              void* d_out, int out_size, void* d_ws, size_t ws_size,
                              hipStream_t stream) {
    const float* out_img = (const float*)d_in[0];
    const float* tgt_img = (const float*)d_in[1];
    float* partial = (float*)d_ws;   // 4096 floats = 16 KB
    gvl_main<<<4096, 256, 0, stream>>>(out_img, tgt_img, partial);
    gvl_final<<<1, 256, 0, stream>>>(partial, (float*)d_out);
}